// Round 2
// baseline (262.232 us; speedup 1.0000x reference)
//
#include <hip/hip_runtime.h>

#define DD 6
#define FF 64
#define NS 30       // 2*D*RANK + D
#define TSTRIDE 32  // padded table row stride (floats) for aligned float4 gathers

__device__ __forceinline__ float fast_sigmoid(float v) {
    return __builtin_amdgcn_rcpf(1.0f + __expf(-v));
}

// Phase 1: per node/edge, mean over D rows then project by W-half (+b for nodes).
// One wave per unit; lane = feature for the mean, lane = output j for the dot.
__global__ __launch_bounds__(256) void precompute_kernel(
    const float* __restrict__ x, const float* __restrict__ e,
    const float* __restrict__ W, const float* __restrict__ b,
    float* __restrict__ xW, float* __restrict__ eW, int N, int E)
{
    int gw   = (blockIdx.x * 256 + threadIdx.x) >> 6;  // wave-uniform
    int lane = threadIdx.x & 63;
    int total = N + E;
    if (gw >= total) return;
    bool isNode = gw < N;
    int u = isNode ? gw : (gw - N);
    const float* src = (isNode ? x : e) + (size_t)u * (DD * FF);

    float acc = 0.f;
    #pragma unroll
    for (int d = 0; d < DD; ++d) acc += src[d * FF + lane];
    acc *= (1.0f / 6.0f);   // xm[u][lane]

    const float* Wp = W + (isNode ? 0 : FF * NS);
    int j = (lane < NS) ? lane : 0;
    float o = 0.f;
    #pragma unroll
    for (int f = 0; f < FF; ++f) {
        float v = __shfl(acc, f, 64);          // readlane broadcast
        o = fmaf(v, Wp[f * NS + j], o);        // W is 15KB -> L1 resident
    }
    if (lane < NS) {
        if (isNode) o += b[lane];
        (isNode ? xW : eW)[(size_t)u * TSTRIDE + lane] = o;
    }
}

// Phase 2 (fused): per NNZ compute s = sigmoid(xW[row]+eW[col]),
// maps = A B^T + diag(C) -> LDS, then block-linear float4 copy-out of
// ALL THREE output streams (attrs + both index rows). The idx write
// stream gives the memory system coalesced work while other waves wait
// on the random table gathers.
__global__ __launch_bounds__(256) void fused_kernel(
    const int* __restrict__ rows, const int* __restrict__ cols,
    const float* __restrict__ xW, const float* __restrict__ eW,
    float* __restrict__ out_idx0, float* __restrict__ out_idx1,
    float* __restrict__ out_attr, int nnz)
{
    __shared__ float mlds[256 * 37];
    __shared__ int   rlds[256];
    __shared__ int   clds[256];
    int tid  = threadIdx.x;
    int base = blockIdx.x * 256;
    int k    = base + tid;
    if (k < nnz) {
        int r = rows[k];
        int c = cols[k];
        rlds[tid] = r;
        clds[tid] = c;
        const float4* xp = (const float4*)(xW + (size_t)r * TSTRIDE);
        const float4* ep = (const float4*)(eW + (size_t)c * TSTRIDE);
        float s[32];
        #pragma unroll
        for (int q = 0; q < 8; ++q) {
            float4 a = xp[q], bb = ep[q];
            s[q*4+0] = a.x + bb.x; s[q*4+1] = a.y + bb.y;
            s[q*4+2] = a.z + bb.z; s[q*4+3] = a.w + bb.w;
        }
        #pragma unroll
        for (int jj = 0; jj < NS; ++jj) s[jj] = fast_sigmoid(s[jj]);

        float* ml = mlds + tid * 37;
        #pragma unroll
        for (int i = 0; i < DD; ++i) {
            float a0 = s[i*2], a1 = s[i*2+1];
            #pragma unroll
            for (int jj = 0; jj < DD; ++jj) {
                float v = fmaf(a0, s[12 + jj*2], a1 * s[12 + jj*2 + 1]);
                if (i == jj) v += s[24 + i];
                ml[i*6 + jj] = v;
            }
        }
    }
    __syncthreads();
    int cnt = nnz - base; if (cnt > 256) cnt = 256;
    int tot = cnt * 36;                      // divisible by 4
    size_t ob = (size_t)base * 36;
    float* ga = out_attr + ob;
    float* g0 = out_idx0 + ob;
    float* g1 = out_idx1 + ob;
    for (int g = tid * 4; g < tot; g += 1024) {
        float va[4], v0[4], v1[4];
        #pragma unroll
        for (int i = 0; i < 4; ++i) {
            int gg = g + i;
            int l  = gg / 36;
            int m  = gg - l * 36;
            int m6 = m / 6;
            va[i] = mlds[l * 37 + m];
            v0[i] = (float)(6 * rlds[l] + m6);
            v1[i] = (float)(6 * clds[l] + (m - m6 * 6));
        }
        *(float4*)(ga + g) = make_float4(va[0], va[1], va[2], va[3]);
        *(float4*)(g0 + g) = make_float4(v0[0], v0[1], v0[2], v0[3]);
        *(float4*)(g1 + g) = make_float4(v1[0], v1[1], v1[2], v1[3]);
    }
}

// Fallback split kernels (used only if ws_size is too small for the tables,
// in which case tables are staged inside the idx0 output region and the idx
// kernel must run AFTER the sheaf kernel has consumed them).
__global__ __launch_bounds__(256) void sheaf_kernel(
    const int* __restrict__ rows, const int* __restrict__ cols,
    const float* __restrict__ xW, const float* __restrict__ eW,
    float* __restrict__ out_attr, int nnz)
{
    __shared__ float mlds[256 * 37];
    int tid  = threadIdx.x;
    int base = blockIdx.x * 256;
    int k    = base + tid;
    if (k < nnz) {
        int r = rows[k];
        int c = cols[k];
        const float4* xp = (const float4*)(xW + (size_t)r * TSTRIDE);
        const float4* ep = (const float4*)(eW + (size_t)c * TSTRIDE);
        float s[32];
        #pragma unroll
        for (int q = 0; q < 8; ++q) {
            float4 a = xp[q], bb = ep[q];
            s[q*4+0] = a.x + bb.x; s[q*4+1] = a.y + bb.y;
            s[q*4+2] = a.z + bb.z; s[q*4+3] = a.w + bb.w;
        }
        #pragma unroll
        for (int jj = 0; jj < NS; ++jj) s[jj] = fast_sigmoid(s[jj]);
        float* ml = mlds + tid * 37;
        #pragma unroll
        for (int i = 0; i < DD; ++i) {
            float a0 = s[i*2], a1 = s[i*2+1];
            #pragma unroll
            for (int jj = 0; jj < DD; ++jj) {
                float v = fmaf(a0, s[12 + jj*2], a1 * s[12 + jj*2 + 1]);
                if (i == jj) v += s[24 + i];
                ml[i*6 + jj] = v;
            }
        }
    }
    __syncthreads();
    int cnt = nnz - base; if (cnt > 256) cnt = 256;
    int tot = cnt * 36;
    float* gp = out_attr + (size_t)base * 36;
    for (int g = tid * 4; g < tot; g += 1024) {
        float v[4];
        #pragma unroll
        for (int i = 0; i < 4; ++i) {
            int gg = g + i;
            int l  = gg / 36;
            int m  = gg - l * 36;
            v[i] = mlds[l * 37 + m];
        }
        *(float4*)(gp + g) = make_float4(v[0], v[1], v[2], v[3]);
    }
}

__global__ __launch_bounds__(256) void idx_kernel(
    const int* __restrict__ rows, const int* __restrict__ cols,
    float* __restrict__ out_idx0, float* __restrict__ out_idx1, int tot)
{
    int g = (blockIdx.x * 256 + threadIdx.x) * 4;
    if (g >= tot) return;
    float v0[4], v1[4];
    #pragma unroll
    for (int i = 0; i < 4; ++i) {
        int gg = g + i;
        int l  = gg / 36;
        int m  = gg - l * 36;
        int m6 = m / 6;
        v0[i] = (float)(6 * rows[l] + m6);
        v1[i] = (float)(6 * cols[l] + (m - m6 * 6));
    }
    *(float4*)(out_idx0 + g) = make_float4(v0[0], v0[1], v0[2], v0[3]);
    *(float4*)(out_idx1 + g) = make_float4(v1[0], v1[1], v1[2], v1[3]);
}

extern "C" void kernel_launch(void* const* d_in, const int* in_sizes, int n_in,
                              void* d_out, int out_size, void* d_ws, size_t ws_size,
                              hipStream_t stream)
{
    const float* x = (const float*)d_in[0];
    const float* e = (const float*)d_in[1];
    const float* W = (const float*)d_in[2];
    const float* b = (const float*)d_in[3];
    const int* hidx = (const int*)d_in[4];

    int N   = in_sizes[0] / (DD * FF);
    int E   = in_sizes[1] / (DD * FF);
    int nnz = in_sizes[4] / 2;
    const int* rows = hidx;
    const int* cols = hidx + nnz;

    float* out = (float*)d_out;
    size_t M = (size_t)nnz * 36;
    float* out_idx0 = out;
    float* out_idx1 = out + M;
    float* out_attr = out + 2 * M;

    size_t tableBytes = ((size_t)N + (size_t)E) * TSTRIDE * sizeof(float);
    bool haveWs = (ws_size >= tableBytes);
    float* xW = haveWs ? (float*)d_ws : out_idx0;   // fallback: stage in idx0 region
    float* eW = xW + (size_t)N * TSTRIDE;

    int totalUnits = N + E;                       // one wave each
    int pcBlocks = (totalUnits + 3) / 4;          // 4 waves per 256-thread block
    precompute_kernel<<<pcBlocks, 256, 0, stream>>>(x, e, W, b, xW, eW, N, E);

    int sBlocks = (nnz + 255) / 256;
    if (haveWs) {
        fused_kernel<<<sBlocks, 256, 0, stream>>>(rows, cols, xW, eW,
                                                  out_idx0, out_idx1, out_attr, nnz);
    } else {
        sheaf_kernel<<<sBlocks, 256, 0, stream>>>(rows, cols, xW, eW, out_attr, nnz);
        int tot = nnz * 36;
        int iBlocks = (tot / 4 + 255) / 256;
        idx_kernel<<<iBlocks, 256, 0, stream>>>(rows, cols, out_idx0, out_idx1, tot);
    }
}

// Round 4
// 172.423 us; speedup vs baseline: 1.5209x; 1.5209x over previous
//
#include <hip/hip_runtime.h>
#include <hip/hip_bf16.h>

#define DD 6
#define FF 64
#define NS 30     // 2*D*RANK + D
#define TS16 32   // bf16 elements per table row (64 B, one uint4-quad)

typedef float fx4 __attribute__((ext_vector_type(4)));   // clang vector: nt-store-compatible

__device__ __forceinline__ float fast_sigmoid(float v) {
    return __builtin_amdgcn_rcpf(1.0f + __expf(-v));
}

__device__ __forceinline__ void nt_store4(float* p, float a, float b, float c, float d) {
    fx4 v = {a, b, c, d};
    __builtin_nontemporal_store(v, (fx4*)p);
}

// Phase 1: per node/edge, mean over D rows then project by W-half (+b for nodes).
// One wave per unit; lane = feature for the mean, lane = output j for the dot.
// Tables stored bf16 (halves gather footprint; logits are O(1) so bf16 abs err <= 2^-8).
__global__ __launch_bounds__(256) void precompute_kernel(
    const float* __restrict__ x, const float* __restrict__ e,
    const float* __restrict__ W, const float* __restrict__ b,
    __hip_bfloat16* __restrict__ xW, __hip_bfloat16* __restrict__ eW, int N, int E)
{
    int gw   = (blockIdx.x * 256 + threadIdx.x) >> 6;  // wave-uniform
    int lane = threadIdx.x & 63;
    if (gw >= N + E) return;
    bool isNode = gw < N;
    int u = isNode ? gw : (gw - N);
    const float* src = (isNode ? x : e) + (size_t)u * (DD * FF);

    float acc = 0.f;
    #pragma unroll
    for (int d = 0; d < DD; ++d) acc += src[d * FF + lane];
    acc *= (1.0f / 6.0f);

    const float* Wp = W + (isNode ? 0 : FF * NS);
    int j = (lane < NS) ? lane : 0;
    float o = 0.f;
    #pragma unroll
    for (int f = 0; f < FF; ++f) {
        float v = __shfl(acc, f, 64);
        o = fmaf(v, Wp[f * NS + j], o);        // W is 15 KB -> L1 resident
    }
    if (lane < NS) {
        if (isNode) o += b[lane];
        (isNode ? xW : eW)[(size_t)u * TS16 + lane] = __float2bfloat16(o);
    }
}

// Phase 2: per NNZ, s = sigmoid(xW[row]+eW[col]); maps = A B^T + diag(C).
// Two-pass per-wave LDS staging (32 nnz slices) -> 18.9 KB/block -> 8 blocks/CU.
// Output written with non-temporal float4 stores (never re-read; keeps L2 for tables).
__global__ __launch_bounds__(256) void sheaf_kernel(
    const int* __restrict__ rows, const int* __restrict__ cols,
    const __hip_bfloat16* __restrict__ xW, const __hip_bfloat16* __restrict__ eW,
    float* __restrict__ out_attr, int nnz)
{
    __shared__ float mlds[4][32 * 37];   // per-wave 4736 B slice, stride 37 (conflict-free)
    int tid  = threadIdx.x;
    int wid  = tid >> 6;
    int lane = tid & 63;
    int bb   = blockIdx.x * 256;
    int k    = bb + tid;
    bool act = k < nnz;

    float mp[36];
    if (act) {
        int r = rows[k];
        int c = cols[k];
        const uint4* xp = (const uint4*)(xW + (size_t)r * TS16);
        const uint4* ep = (const uint4*)(eW + (size_t)c * TS16);
        uint4 xa0 = xp[0], xa1 = xp[1], xa2 = xp[2], xa3 = xp[3];
        uint4 ea0 = ep[0], ea1 = ep[1], ea2 = ep[2], ea3 = ep[3];
        uint wx[16] = {xa0.x, xa0.y, xa0.z, xa0.w, xa1.x, xa1.y, xa1.z, xa1.w,
                       xa2.x, xa2.y, xa2.z, xa2.w, xa3.x, xa3.y, xa3.z, xa3.w};
        uint we[16] = {ea0.x, ea0.y, ea0.z, ea0.w, ea1.x, ea1.y, ea1.z, ea1.w,
                       ea2.x, ea2.y, ea2.z, ea2.w, ea3.x, ea3.y, ea3.z, ea3.w};
        float s[NS];
        #pragma unroll
        for (int j2 = 0; j2 < NS; ++j2) {
            uint ux = (j2 & 1) ? (wx[j2 >> 1] & 0xffff0000u) : (wx[j2 >> 1] << 16);
            uint ue = (j2 & 1) ? (we[j2 >> 1] & 0xffff0000u) : (we[j2 >> 1] << 16);
            s[j2] = fast_sigmoid(__uint_as_float(ux) + __uint_as_float(ue));
        }
        #pragma unroll
        for (int i = 0; i < DD; ++i) {
            float a0 = s[i * 2], a1 = s[i * 2 + 1];
            #pragma unroll
            for (int jj = 0; jj < DD; ++jj) {
                float v = fmaf(a0, s[12 + jj * 2], a1 * s[13 + jj * 2]);
                if (i == jj) v += s[24 + i];
                mp[i * 6 + jj] = v;
            }
        }
    }

    float* wl = mlds[wid];
    int wbase = bb + wid * 64;
    #pragma unroll
    for (int h = 0; h < 2; ++h) {
        if (h) __syncthreads();          // LDS reuse: previous copy done
        if (act && (lane >> 5) == h) {
            float* ml = wl + (lane & 31) * 37;
            #pragma unroll
            for (int m = 0; m < 36; ++m) ml[m] = mp[m];
        }
        __syncthreads();                 // writes visible to whole block
        int cnt = nnz - (wbase + h * 32);
        if (cnt > 32) cnt = 32;
        if (cnt > 0) {
            int tot = cnt * 36;          // divisible by 4
            float* gp = out_attr + (size_t)(wbase + h * 32) * 36;
            for (int g = lane * 4; g < tot; g += 256) {
                int l = g / 36;
                int m = g - l * 36;      // 4-aligned, never crosses a row
                const float* mlp = wl + l * 37 + m;
                nt_store4(gp + g, mlp[0], mlp[1], mlp[2], mlp[3]);
            }
        }
    }
}

// Phase 3: index outputs, non-temporal float4 stores.
__global__ __launch_bounds__(256) void idx_kernel(
    const int* __restrict__ rows, const int* __restrict__ cols,
    float* __restrict__ out_idx0, float* __restrict__ out_idx1, int tot)
{
    int g = (blockIdx.x * 256 + threadIdx.x) * 4;
    if (g >= tot) return;
    float v0[4], v1[4];
    #pragma unroll
    for (int i = 0; i < 4; ++i) {
        int gg = g + i;
        int l  = gg / 36;
        int m  = gg - l * 36;
        int m6 = m / 6;
        v0[i] = (float)(6 * rows[l] + m6);
        v1[i] = (float)(6 * cols[l] + (m - m6 * 6));
    }
    nt_store4(out_idx0 + g, v0[0], v0[1], v0[2], v0[3]);
    nt_store4(out_idx1 + g, v1[0], v1[1], v1[2], v1[3]);
}

extern "C" void kernel_launch(void* const* d_in, const int* in_sizes, int n_in,
                              void* d_out, int out_size, void* d_ws, size_t ws_size,
                              hipStream_t stream)
{
    const float* x = (const float*)d_in[0];
    const float* e = (const float*)d_in[1];
    const float* W = (const float*)d_in[2];
    const float* b = (const float*)d_in[3];
    const int* hidx = (const int*)d_in[4];

    int N   = in_sizes[0] / (DD * FF);
    int E   = in_sizes[1] / (DD * FF);
    int nnz = in_sizes[4] / 2;
    const int* rows = hidx;
    const int* cols = hidx + nnz;

    float* out = (float*)d_out;
    size_t M = (size_t)nnz * 36;
    float* out_idx0 = out;
    float* out_idx1 = out + M;
    float* out_attr = out + 2 * M;

    // bf16 tables: 7.7 MB. Prefer d_ws; fallback stages inside the idx0 output
    // region (overwritten only by idx_kernel, which runs after sheaf_kernel).
    size_t tableBytes = ((size_t)N + (size_t)E) * TS16 * sizeof(__hip_bfloat16);
    __hip_bfloat16* xW = (ws_size >= tableBytes) ? (__hip_bfloat16*)d_ws
                                                 : (__hip_bfloat16*)out_idx0;
    __hip_bfloat16* eW = xW + (size_t)N * TS16;

    int pcBlocks = (N + E + 3) / 4;               // 4 waves per 256-thread block
    precompute_kernel<<<pcBlocks, 256, 0, stream>>>(x, e, W, b, xW, eW, N, E);

    int sBlocks = (nnz + 255) / 256;
    sheaf_kernel<<<sBlocks, 256, 0, stream>>>(rows, cols, xW, eW, out_attr, nnz);

    int tot = nnz * 36;
    int iBlocks = (tot / 4 + 255) / 256;
    idx_kernel<<<iBlocks, 256, 0, stream>>>(rows, cols, out_idx0, out_idx1, tot);
}

// Round 5
// 130.863 us; speedup vs baseline: 2.0039x; 1.3176x over previous
//
#include <hip/hip_runtime.h>
#include <hip/hip_bf16.h>

#define DD 6
#define FF 64
#define NS 30     // 2*D*RANK + D
#define TS16 32   // bf16 elements per table row (64 B)
#define UPB 32    // units per block in precompute

typedef float fx4 __attribute__((ext_vector_type(4)));

__device__ __forceinline__ float fast_sigmoid(float v) {
    return __builtin_amdgcn_rcpf(1.0f + __expf(-v));
}
__device__ __forceinline__ void nt_store4(float* p, float a, float b, float c, float d) {
    fx4 v = {a, b, c, d};
    __builtin_nontemporal_store(v, (fx4*)p);
}

// Precompute: blocks [0,nbN) handle nodes, [nbN,nbN+nbE) edges (no mixed W halves).
// Phase A: block stages 32 unit-means in LDS (stride 68 floats, 16B-aligned rows).
// Phase B: each wave processes its 8 units in pairs — low half-wave = unit 2t,
// high = 2t+1; ds_read_b128 uniform-broadcast of the mean + W column in VGPRs.
__global__ __launch_bounds__(256) void precompute_kernel(
    const float* __restrict__ x, const float* __restrict__ e,
    const float* __restrict__ W, const float* __restrict__ bias,
    __hip_bfloat16* __restrict__ xW, __hip_bfloat16* __restrict__ eW,
    int N, int E, int nbN)
{
    __shared__ float means[UPB][68];
    bool isNode = (int)blockIdx.x < nbN;
    int ucount  = isNode ? N : E;
    int ubase   = (isNode ? blockIdx.x : (blockIdx.x - nbN)) * UPB;
    const float* src = isNode ? x : e;
    const float* Wp  = W + (isNode ? 0 : FF * NS);
    __hip_bfloat16* dst = isNode ? xW : eW;

    int tid = threadIdx.x, wid = tid >> 6, lane = tid & 63;

    // Phase A: wave computes means for its 8 consecutive units (coalesced reads).
    #pragma unroll
    for (int i = 0; i < 8; ++i) {
        int s = wid * 8 + i;
        int u = ubase + s;
        float m = 0.f;
        if (u < ucount) {
            const float* p = src + (size_t)u * (DD * FF) + lane;
            #pragma unroll
            for (int d = 0; d < DD; ++d) m += p[d * FF];
        }
        means[s][lane] = m * (1.0f / 6.0f);
    }
    __syncthreads();

    // W column for this lane's output j (both half-waves use the same j range).
    int j30 = lane & 31;
    bool jval = j30 < NS;
    int j = jval ? j30 : 0;
    float wreg[FF];
    #pragma unroll
    for (int f = 0; f < FF; ++f) wreg[f] = Wp[f * NS + j];   // 15 KB, L1-resident
    float bj = isNode ? bias[j] : 0.f;

    // Phase B: unit pairs; summation order f=0..63 matches the reference loop.
    #pragma unroll
    for (int t = 0; t < 4; ++t) {
        int sl = wid * 8 + 2 * t + (lane >> 5);
        int u  = ubase + sl;
        const fx4* mp4 = (const fx4*)(&means[sl][0]);
        float o = bj;
        #pragma unroll
        for (int q = 0; q < 16; ++q) {
            fx4 m4 = mp4[q];
            o = fmaf(m4.x, wreg[4 * q + 0], o);
            o = fmaf(m4.y, wreg[4 * q + 1], o);
            o = fmaf(m4.z, wreg[4 * q + 2], o);
            o = fmaf(m4.w, wreg[4 * q + 3], o);
        }
        if (jval && u < ucount)
            dst[(size_t)u * TS16 + j30] = __float2bfloat16(o);
    }
}

// Fused: per NNZ gather bf16 logits, sigmoid, maps -> LDS (2-pass, stride 37),
// then one block-linear copy loop writes ALL THREE output streams with nt float4
// stores (no L2 pollution -> tables stay cached; idx dispatch eliminated).
__global__ __launch_bounds__(256) void fused_kernel(
    const int* __restrict__ rows, const int* __restrict__ cols,
    const __hip_bfloat16* __restrict__ xW, const __hip_bfloat16* __restrict__ eW,
    float* __restrict__ out_idx0, float* __restrict__ out_idx1,
    float* __restrict__ out_attr, int nnz)
{
    __shared__ float mlds[4][32 * 37];
    __shared__ int rlds[256], clds[256];
    int tid  = threadIdx.x, wid = tid >> 6, lane = tid & 63;
    int bb   = blockIdx.x * 256;
    int k    = bb + tid;
    bool act = k < nnz;

    float mp[36];
    if (act) {
        int r = rows[k];
        int c = cols[k];
        rlds[tid] = r; clds[tid] = c;
        const uint4* xp = (const uint4*)(xW + (size_t)r * TS16);
        const uint4* ep = (const uint4*)(eW + (size_t)c * TS16);
        uint4 xa0 = xp[0], xa1 = xp[1], xa2 = xp[2], xa3 = xp[3];
        uint4 ea0 = ep[0], ea1 = ep[1], ea2 = ep[2], ea3 = ep[3];
        uint wx[16] = {xa0.x, xa0.y, xa0.z, xa0.w, xa1.x, xa1.y, xa1.z, xa1.w,
                       xa2.x, xa2.y, xa2.z, xa2.w, xa3.x, xa3.y, xa3.z, xa3.w};
        uint we[16] = {ea0.x, ea0.y, ea0.z, ea0.w, ea1.x, ea1.y, ea1.z, ea1.w,
                       ea2.x, ea2.y, ea2.z, ea2.w, ea3.x, ea3.y, ea3.z, ea3.w};
        float s[NS];
        #pragma unroll
        for (int j2 = 0; j2 < NS; ++j2) {
            uint ux = (j2 & 1) ? (wx[j2 >> 1] & 0xffff0000u) : (wx[j2 >> 1] << 16);
            uint ue = (j2 & 1) ? (we[j2 >> 1] & 0xffff0000u) : (we[j2 >> 1] << 16);
            s[j2] = fast_sigmoid(__uint_as_float(ux) + __uint_as_float(ue));
        }
        #pragma unroll
        for (int i = 0; i < DD; ++i) {
            float a0 = s[i * 2], a1 = s[i * 2 + 1];
            #pragma unroll
            for (int jj = 0; jj < DD; ++jj) {
                float v = fmaf(a0, s[12 + jj * 2], a1 * s[13 + jj * 2]);
                if (i == jj) v += s[24 + i];
                mp[i * 6 + jj] = v;
            }
        }
    }

    float* wl = mlds[wid];
    int wbase = bb + wid * 64;
    #pragma unroll
    for (int h = 0; h < 2; ++h) {
        if (h) __syncthreads();          // LDS slice reuse
        if (act && (lane >> 5) == h) {
            float* ml = wl + (lane & 31) * 37;
            #pragma unroll
            for (int m = 0; m < 36; ++m) ml[m] = mp[m];
        }
        __syncthreads();
        int b2  = wbase + h * 32;
        int cnt = nnz - b2; if (cnt > 32) cnt = 32;
        if (cnt > 0) {
            int tot = cnt * 36;                  // 4-divisible
            size_t ob = (size_t)b2 * 36;
            float* ga = out_attr + ob;
            float* g0 = out_idx0 + ob;
            float* g1 = out_idx1 + ob;
            int lb = wid * 64 + h * 32;          // block-local nnz base
            for (int g = lane * 4; g < tot; g += 256) {
                int l = g / 36;
                int m = g - l * 36;              // 4-aligned; m+3 <= 35: same l for all 4
                const float* mlp = wl + l * 37 + m;
                int rr = rlds[lb + l], cc = clds[lb + l];
                float v0[4], v1[4];
                #pragma unroll
                for (int i = 0; i < 4; ++i) {
                    int mm = m + i;
                    int m6 = mm / 6;
                    v0[i] = (float)(6 * rr + m6);
                    v1[i] = (float)(6 * cc + (mm - m6 * 6));
                }
                nt_store4(ga + g, mlp[0], mlp[1], mlp[2], mlp[3]);
                nt_store4(g0 + g, v0[0], v0[1], v0[2], v0[3]);
                nt_store4(g1 + g, v1[0], v1[1], v1[2], v1[3]);
            }
        }
    }
}

// Fallback split kernels (used only if ws_size can't hold the tables; tables are
// then staged in the idx0 output region, so idx writes must come last).
__global__ __launch_bounds__(256) void sheaf_kernel(
    const int* __restrict__ rows, const int* __restrict__ cols,
    const __hip_bfloat16* __restrict__ xW, const __hip_bfloat16* __restrict__ eW,
    float* __restrict__ out_attr, int nnz)
{
    __shared__ float mlds[4][32 * 37];
    int tid = threadIdx.x, wid = tid >> 6, lane = tid & 63;
    int bb  = blockIdx.x * 256;
    int k   = bb + tid;
    bool act = k < nnz;
    float mp[36];
    if (act) {
        int r = rows[k];
        int c = cols[k];
        const uint4* xp = (const uint4*)(xW + (size_t)r * TS16);
        const uint4* ep = (const uint4*)(eW + (size_t)c * TS16);
        uint4 xa0 = xp[0], xa1 = xp[1], xa2 = xp[2], xa3 = xp[3];
        uint4 ea0 = ep[0], ea1 = ep[1], ea2 = ep[2], ea3 = ep[3];
        uint wx[16] = {xa0.x, xa0.y, xa0.z, xa0.w, xa1.x, xa1.y, xa1.z, xa1.w,
                       xa2.x, xa2.y, xa2.z, xa2.w, xa3.x, xa3.y, xa3.z, xa3.w};
        uint we[16] = {ea0.x, ea0.y, ea0.z, ea0.w, ea1.x, ea1.y, ea1.z, ea1.w,
                       ea2.x, ea2.y, ea2.z, ea2.w, ea3.x, ea3.y, ea3.z, ea3.w};
        float s[NS];
        #pragma unroll
        for (int j2 = 0; j2 < NS; ++j2) {
            uint ux = (j2 & 1) ? (wx[j2 >> 1] & 0xffff0000u) : (wx[j2 >> 1] << 16);
            uint ue = (j2 & 1) ? (we[j2 >> 1] & 0xffff0000u) : (we[j2 >> 1] << 16);
            s[j2] = fast_sigmoid(__uint_as_float(ux) + __uint_as_float(ue));
        }
        #pragma unroll
        for (int i = 0; i < DD; ++i) {
            float a0 = s[i * 2], a1 = s[i * 2 + 1];
            #pragma unroll
            for (int jj = 0; jj < DD; ++jj) {
                float v = fmaf(a0, s[12 + jj * 2], a1 * s[13 + jj * 2]);
                if (i == jj) v += s[24 + i];
                mp[i * 6 + jj] = v;
            }
        }
    }
    float* wl = mlds[wid];
    int wbase = bb + wid * 64;
    #pragma unroll
    for (int h = 0; h < 2; ++h) {
        if (h) __syncthreads();
        if (act && (lane >> 5) == h) {
            float* ml = wl + (lane & 31) * 37;
            #pragma unroll
            for (int m = 0; m < 36; ++m) ml[m] = mp[m];
        }
        __syncthreads();
        int b2  = wbase + h * 32;
        int cnt = nnz - b2; if (cnt > 32) cnt = 32;
        if (cnt > 0) {
            int tot = cnt * 36;
            float* gp = out_attr + (size_t)b2 * 36;
            for (int g = lane * 4; g < tot; g += 256) {
                int l = g / 36;
                int m = g - l * 36;
                const float* mlp = wl + l * 37 + m;
                nt_store4(gp + g, mlp[0], mlp[1], mlp[2], mlp[3]);
            }
        }
    }
}

__global__ __launch_bounds__(256) void idx_kernel(
    const int* __restrict__ rows, const int* __restrict__ cols,
    float* __restrict__ out_idx0, float* __restrict__ out_idx1, int tot)
{
    int g = (blockIdx.x * 256 + threadIdx.x) * 4;
    if (g >= tot) return;
    float v0[4], v1[4];
    #pragma unroll
    for (int i = 0; i < 4; ++i) {
        int gg = g + i;
        int l  = gg / 36;
        int m  = gg - l * 36;
        int m6 = m / 6;
        v0[i] = (float)(6 * rows[l] + m6);
        v1[i] = (float)(6 * cols[l] + (m - m6 * 6));
    }
    nt_store4(out_idx0 + g, v0[0], v0[1], v0[2], v0[3]);
    nt_store4(out_idx1 + g, v1[0], v1[1], v1[2], v1[3]);
}

extern "C" void kernel_launch(void* const* d_in, const int* in_sizes, int n_in,
                              void* d_out, int out_size, void* d_ws, size_t ws_size,
                              hipStream_t stream)
{
    const float* x = (const float*)d_in[0];
    const float* e = (const float*)d_in[1];
    const float* W = (const float*)d_in[2];
    const float* b = (const float*)d_in[3];
    const int* hidx = (const int*)d_in[4];

    int N   = in_sizes[0] / (DD * FF);
    int E   = in_sizes[1] / (DD * FF);
    int nnz = in_sizes[4] / 2;
    const int* rows = hidx;
    const int* cols = hidx + nnz;

    float* out = (float*)d_out;
    size_t M = (size_t)nnz * 36;
    float* out_idx0 = out;
    float* out_idx1 = out + M;
    float* out_attr = out + 2 * M;

    size_t tableBytes = ((size_t)N + (size_t)E) * TS16 * sizeof(__hip_bfloat16);
    bool haveWs = (ws_size >= tableBytes);
    __hip_bfloat16* xW = haveWs ? (__hip_bfloat16*)d_ws
                                : (__hip_bfloat16*)out_idx0;   // fallback staging
    __hip_bfloat16* eW = xW + (size_t)N * TS16;

    int nbN = (N + UPB - 1) / UPB;
    int nbE = (E + UPB - 1) / UPB;
    precompute_kernel<<<nbN + nbE, 256, 0, stream>>>(x, e, W, b, xW, eW, N, E, nbN);

    int sBlocks = (nnz + 255) / 256;
    if (haveWs) {
        fused_kernel<<<sBlocks, 256, 0, stream>>>(rows, cols, xW, eW,
                                                  out_idx0, out_idx1, out_attr, nnz);
    } else {
        sheaf_kernel<<<sBlocks, 256, 0, stream>>>(rows, cols, xW, eW, out_attr, nnz);
        int tot = nnz * 36;
        int iBlocks = (tot / 4 + 255) / 256;
        idx_kernel<<<iBlocks, 256, 0, stream>>>(rows, cols, out_idx0, out_idx1, tot);
    }
}